// Round 12
// baseline (204.603 us; speedup 1.0000x reference)
//
#include <hip/hip_runtime.h>

#define NPIX 4096
#define NT 1024
#define PPT 4
#define EMPTY 0xFFFFFFFFu
#define FLAGMAGIC 0x00C0FFEEu
#define HIMASK 0xFFFFFFFF00000000ull

__global__ void ph_zero_kernel(float* out) { out[0] = 0.0f; }

__device__ __forceinline__ float kval(unsigned k) {
  unsigned u = (k & 0x80000000u) ? (k & 0x7FFFFFFFu) : ~k;
  return __uint_as_float(u);
}

__device__ __forceinline__ void memfence_compiler() {
  __asm__ volatile("" ::: "memory");
  __builtin_amdgcn_sched_barrier(0);
}

__global__ __launch_bounds__(NT) void ph_pass_kernel(const float* __restrict__ x,
                                                     float* __restrict__ out,
                                                     unsigned long long* __restrict__ ws64,
                                                     int use_ws) {
  // One 64 KB pool, phase-aliased:
  //  [0,32K)  : hash (hkey 16K | hval 16K) -> edge sort buffers A|B -> sorted edges
  //  [32K,48K): key32 u32[4096]            -> clobbered by node records
  //  [48K,56K): label u16[4096]            -> clobbered by node records
  //  [32K,64K): node u64[4096] = creatorKey<<32 | parent   (Kruskal phase)
  __shared__ unsigned long long pool[2 * NPIX];
  __shared__ unsigned wredu[32];           // wave staging: [0..15] raw, [16..31] scanned
  __shared__ unsigned claim[NPIX];         // 16 KB: seq-tagged claim cells (no reset)

  unsigned long long* sbuf = pool;
  unsigned* hkey = (unsigned*)pool;
  unsigned* hval = hkey + NPIX;
  unsigned* key32 = (unsigned*)(pool + NPIX);
  unsigned short* label = (unsigned short*)(pool + NPIX + NPIX / 2);
  unsigned long long* node = pool + NPIX;

  const int blk = blockIdx.x;            // 24 blocks: b(4) x c(3) x pass(2)
  const int b = blk / 6;
  const int rem = blk % 6;
  const int c = (rem >> 1) + 1;          // classes 1..3
  const int pass = rem & 1;              // 0 = sublevel 8-conn (H0), 1 = superlevel 4-conn (H1)
  const float* img = x + (size_t)(b * 4 + c) * NPIX;
  const int tid = threadIdx.x;
  const int lane = tid & 63, wid = tid >> 6;
  const int ndirs = pass ? 4 : 8;
  const int drr[8] = {-1, 1, 0, 0, -1, -1, 1, 1};
  const int dcc[8] = { 0, 0,-1, 1, -1,  1, -1, 1};

  // --- phase 1: monotone keys via float4 (pass 1 negates); hash+claim init; min ---
  unsigned lmin = EMPTY;
  {
    const float4 v4 = ((const float4*)img)[tid];
    float fv[4] = {v4.x, v4.y, v4.z, v4.w};
    #pragma unroll
    for (int t = 0; t < 4; t++) {
      float f = pass ? -fv[t] : fv[t];
      unsigned u = __float_as_uint(f);
      unsigned k = (u & 0x80000000u) ? ~u : (u | 0x80000000u);
      key32[4 * tid + t] = k;            // contiguous -> b128
      lmin = min(lmin, k);
    }
    #pragma unroll
    for (int t = 0; t < 4; t++) {
      pool[4 * tid + t] = ~0ull;         // hkey/hval = EMPTY (region [0,32K))
      claim[4 * tid + t] = 0;
    }
  }
  for (int off = 32; off > 0; off >>= 1)
    lmin = min(lmin, (unsigned)__shfl_xor((int)lmin, off));
  if (lane == 0) wredu[wid] = lmin;
  __syncthreads();
  unsigned vmink = wredu[0];
  #pragma unroll
  for (int w = 1; w < 16; w++) vmink = min(vmink, wredu[w]);

  // --- phase 2: watershed pointers, then per-thread chase-to-root (no rounds).
  //     Writes only move labels toward the fixed root -> race-safe, terminates. ---
  for (int i = tid; i < NPIX; i += NT) {
    unsigned long long best = ((unsigned long long)key32[i] << 32) | (unsigned)i;
    int bestnb = i;
    int r = i >> 6, cc = i & 63;
    for (int d = 0; d < ndirs; d++) {
      int rr = r + drr[d], c2 = cc + dcc[d];
      if ((unsigned)rr >= 64u || (unsigned)c2 >= 64u) continue;
      int nb = (rr << 6) | c2;
      unsigned long long pn = ((unsigned long long)key32[nb] << 32) | (unsigned)nb;
      if (pn < best) { best = pn; bestnb = nb; }
    }
    label[i] = (unsigned short)bestnb;
  }
  __syncthreads();
  for (int t = 0; t < PPT; t++) {
    int i = tid + t * NT;
    unsigned short l = label[i];
    unsigned short p = label[l];
    while (p != l) { l = p; p = label[l]; }  // monotone ancestor chase
    label[i] = l;
  }
  __syncthreads();

  // --- phase 3: inter-basin edges deduped to min weight per basin pair ---
  const int pdr[4] = {1, 0, 1,  1};
  const int pdc[4] = {0, 1, 1, -1};
  const int npd = pass ? 2 : 4;
  for (int i = tid; i < NPIX; i += NT) {
    int r = i >> 6, cc = i & 63;
    unsigned la = label[i];
    unsigned ki = key32[i];
    for (int d = 0; d < npd; d++) {
      int rr = r + pdr[d], c2 = cc + pdc[d];
      if ((unsigned)rr >= 64u || (unsigned)c2 >= 64u) continue;
      int nb = (rr << 6) | c2;
      unsigned lb = label[nb];
      if (lb == la) continue;
      unsigned wkey = max(ki, key32[nb]);      // weight = max endpoint key
      unsigned pk = la < lb ? ((la << 12) | lb) : ((lb << 12) | la);
      unsigned h = (pk * 2654435761u) >> 20;
      while (true) {
        unsigned old = atomicCAS(&hkey[h], EMPTY, pk);
        if (old == EMPTY || old == pk) { atomicMin(&hval[h], wkey); break; }
        h = (h + 1) & (NPIX - 1);
      }
    }
  }
  __syncthreads();

  // --- phase 4: stage hash+keys to regs; u32 shfl scan; write edges + nodes ---
  unsigned long long item[PPT];
  unsigned mykeys[PPT];
  int cnt = 0;
  #pragma unroll
  for (int q = 0; q < PPT; q++) {
    int s = 4 * tid + q;
    unsigned pk = hkey[s];
    if (pk != EMPTY) item[cnt++] = (((unsigned long long)hval[s]) << 32) | pk;
  }
  #pragma unroll
  for (int t = 0; t < PPT; t++) mykeys[t] = key32[4 * tid + t];  // b128 read
  __syncthreads();                       // all reads of pool[0..56K) done
  unsigned inc = (unsigned)cnt;
  for (int off = 1; off < 64; off <<= 1) {
    unsigned v = (unsigned)__shfl_up((int)inc, off);
    if (lane >= off) inc += v;
  }
  if (lane == 63) wredu[wid] = inc;
  __syncthreads();
  if (wid == 0) {                        // scan the 16 wave totals in wave 0
    unsigned wv = (lane < 16) ? wredu[lane] : 0u;
    for (int off = 1; off < 16; off <<= 1) {
      unsigned v = (unsigned)__shfl_up((int)wv, off);
      if (lane >= off) wv += v;
    }
    if (lane < 16) wredu[16 + lane] = wv;
  }
  __syncthreads();
  const int M = (int)wredu[31];
  const unsigned wbase = (wid == 0) ? 0u : wredu[16 + wid - 1];
  const int base = (int)(wbase + inc) - cnt;
  for (int q = 0; q < cnt; q++) sbuf[base + q] = item[q];
  #pragma unroll
  for (int t = 0; t < PPT; t++) {
    int i = 4 * tid + t;
    node[i] = (((unsigned long long)mykeys[t]) << 32) | (unsigned)i;  // singleton
  }
  for (int i = M + tid; i < NPIX; i += NT) sbuf[i] = ~0ull;           // pad
  __syncthreads();

  // --- phase 5: sort edges ascending by weight key ---
  if (M <= 2048) {
    // Hybrid bitonic on 2048: j<64 via shfl_xor (no barrier); j in [64,512] via
    // ping-pong LDS (A=pool[0..2048), B=pool[2048..4096)); j=1024 in-thread.
    unsigned long long v0 = sbuf[tid];
    unsigned long long v1 = sbuf[tid + 1024];
    const int i0 = tid, i1 = tid + 1024;
    auto regstage = [&](int k, int j) {
      unsigned long long p0 = __shfl_xor(v0, j);
      unsigned long long p1 = __shfl_xor(v1, j);
      bool m0 = (((i0 & j) == 0) == ((i0 & k) == 0));
      bool m1 = (((i1 & j) == 0) == ((i1 & k) == 0));
      v0 = m0 ? (v0 < p0 ? v0 : p0) : (v0 > p0 ? v0 : p0);
      v1 = m1 ? (v1 < p1 ? v1 : p1) : (v1 > p1 ? v1 : p1);
    };
    int buf = 1;
    for (int k = 2; k <= 64; k <<= 1)
      for (int j = k >> 1; j >= 1; j >>= 1) regstage(k, j);
    for (int k = 128; k <= 2048; k <<= 1) {
      for (int j = k >> 1; j >= 64; j >>= 1) {
        if (j == 1024) {                 // partner is own other element; ascending
          if (v0 > v1) { unsigned long long t = v0; v0 = v1; v1 = t; }
        } else {
          unsigned long long* bp = pool + (buf ? 2048 : 0);
          bp[tid] = v0; bp[tid + 1024] = v1;
          __syncthreads();
          unsigned long long p0 = bp[tid ^ j];
          unsigned long long p1 = bp[(tid ^ j) + 1024];
          bool m0 = (((i0 & j) == 0) == ((i0 & k) == 0));
          bool m1 = (((i1 & j) == 0) == ((i1 & k) == 0));
          v0 = m0 ? (v0 < p0 ? v0 : p0) : (v0 > p0 ? v0 : p0);
          v1 = m1 ? (v1 < p1 ? v1 : p1) : (v1 > p1 ? v1 : p1);
          buf ^= 1;
        }
      }
      for (int j = 32; j >= 1; j >>= 1) regstage(k, j);
    }
    sbuf[tid] = v0; sbuf[tid + 1024] = v1;   // final: back to A for Kruskal
    __syncthreads();
  } else {
    // fallback: in-place bitonic on 4096 (never hit for this input shape)
    for (int k = 2; k <= NPIX; k <<= 1) {
      for (int j = k >> 1; j > 0; j >>= 1) {
        for (int i = tid; i < NPIX; i += NT) {
          int ixj = i ^ j;
          if (ixj > i) {
            unsigned long long va = sbuf[i], vb = sbuf[ixj];
            bool up = ((i & k) == 0);
            if ((va > vb) == up) { sbuf[i] = vb; sbuf[ixj] = va; }
          }
        }
        __syncthreads();
      }
    }
  }

  // --- phase 6: wave-parallel Kruskal (wave 0), claim-based parallel commit,
  //     path-halving finds (key-preserving u64 writes; single wave -> no tearing,
  //     halving keeps forest shallow -> NO block-wide flattens, zero barriers).
  //     Round = claims -> winner test -> commits -> re-finds, compiler-fenced so
  //     commit stores are in program order before loser re-find loads. ---
  double sumsq = 0.0;
  float maxp = 0.0f;
  int pcnt = 0;
  if (wid == 0) {
    unsigned seq = 0;                    // monotone claim tag (no claim resets)
    const int nbat = (M + 63) >> 6;
    for (int bb = 0; bb < nbat; bb++) {
      const int j = (bb << 6) + lane;
      const bool act = (j < M);
      unsigned long long e = act ? sbuf[j] : ~0ull;
      const unsigned wk = (unsigned)(e >> 32);
      const unsigned pk = (unsigned)(e & 0xFFFFFFu);
      unsigned xa = 0, xb = 0;
      unsigned long long recA = 0, recB = 0;
      bool pending = false;
      if (act) {
        xa = pk >> 12; xb = pk & 0xFFFu;
        recA = node[xa];
        recB = node[xb];
        while ((unsigned)recA != xa) {       // find A with path halving
          unsigned p = (unsigned)recA;
          unsigned long long rp = node[p];
          unsigned gp = (unsigned)rp;
          if (gp != p) node[xa] = (recA & HIMASK) | gp;
          xa = p; recA = rp;
        }
        while ((unsigned)recB != xb) {       // find B with path halving
          unsigned p = (unsigned)recB;
          unsigned long long rp = node[p];
          unsigned gp = (unsigned)rp;
          if (gp != p) node[xb] = (recB & HIMASK) | gp;
          xb = p; recB = rp;
        }
        pending = (xa != xb);
      }
      while (__ballot(pending)) {
        seq++;
        const unsigned myval = (seq << 6) | (63u - (unsigned)lane);
        // region 1: claims (smaller lane = earlier edge = higher priority)
        if (pending) {
          atomicMax(&claim[xa], myval);
          atomicMax(&claim[xb], myval);
        }
        memfence_compiler();
        // region 2: winner test (sees ALL lanes' claims: wave lockstep)
        bool winner = false;
        if (pending)
          winner = (claim[xa] == myval) & (claim[xb] == myval);
        memfence_compiler();
        // region 3: commits (winners pairwise root-disjoint -> commute)
        if (winner) {
          unsigned t_elder, t_young;
          unsigned long long t_yrec;
          if (recA < recB) { t_elder = xa; t_young = xb; t_yrec = recB; }
          else             { t_elder = xb; t_young = xa; t_yrec = recA; }
          const unsigned ky = (unsigned)(t_yrec >> 32);
          if (wk > ky) {                 // strictly positive persistence
            float pers = kval(wk) - kval(ky);
            sumsq += (double)pers * (double)pers;
            maxp = fmaxf(maxp, pers);
            pcnt++;
          }
          node[t_young] = (t_yrec & HIMASK) | t_elder;
          pending = false;
        }
        memfence_compiler();
        // region 4: losers re-find (halving) AFTER all commits of this round
        if (pending) {
          recA = node[xa];
          while ((unsigned)recA != xa) {
            unsigned p = (unsigned)recA;
            unsigned long long rp = node[p];
            unsigned gp = (unsigned)rp;
            if (gp != p) node[xa] = (recA & HIMASK) | gp;
            xa = p; recA = rp;
          }
          recB = node[xb];
          while ((unsigned)recB != xb) {
            unsigned p = (unsigned)recB;
            unsigned long long rp = node[p];
            unsigned gp = (unsigned)rp;
            if (gp != p) node[xb] = (recB & HIMASK) | gp;
            xb = p; recB = rp;
          }
          pending = (xa != xb);
        }
      }
    }
    // reduce lane accumulators to lane 0
    for (int off = 32; off > 0; off >>= 1) {
      sumsq += __shfl_xor(sumsq, off);
      maxp = fmaxf(maxp, __shfl_xor(maxp, off));
      pcnt += __shfl_xor(pcnt, off);
    }
  }

  // --- phase 7: per-block contribution (wave 0 only; no trailing barrier needed) ---
  float contrib = 0.0f;
  if (tid == 0) {
    if (pass == 0) {
      const int nf0 = (c == 3) ? 2 : 1;      // TOPO H0: c1->1, c2->1, c3->2
      float vmin = kval(vmink);              // essential birth = global min
      if (nf0 == 1) {
        contrib = vmin * vmin + (float)sumsq;
      } else if (pcnt >= 1) {
        contrib = vmin * vmin + (1.0f - maxp) * (1.0f - maxp)
                + (float)(sumsq - (double)maxp * (double)maxp);
      } else {
        contrib = vmin * vmin + 1.0f;
      }
    } else {
      const int nf1 = (c == 2) ? 1 : 0;      // TOPO H1: c1->0, c2->1, c3->0
      if (nf1 == 0) contrib = (float)sumsq;
      else contrib = (pcnt >= 1)
        ? ((1.0f - maxp) * (1.0f - maxp) + (float)(sumsq - (double)maxp * (double)maxp))
        : 1.0f;
    }
    contrib *= 0.25f;                        // / B, B = 4
    if (use_ws) {
      // publish (value<<32 | magic) in one device-scope atomic
      atomicExch(&ws64[blk],
                 (((unsigned long long)__float_as_uint(contrib)) << 32) | FLAGMAGIC);
    } else {
      atomicAdd(out, contrib);               // out pre-zeroed by ph_zero_kernel
    }
  }
  // --- block 0 wave 0: gather all 24 contributions, write out ---
  if (use_ws && blk == 0 && wid == 0) {
    float v = 0.0f;
    if (lane < 24) {
      while (true) {
        unsigned long long r = atomicAdd(&ws64[lane], 0ull);  // device-coherent read
        if ((unsigned)r == FLAGMAGIC) { v = __uint_as_float((unsigned)(r >> 32)); break; }
      }
    }
    for (int off = 32; off > 0; off >>= 1) v += __shfl_xor(v, off);
    if (lane == 0) out[0] = v;
  }
}

extern "C" void kernel_launch(void* const* d_in, const int* in_sizes, int n_in,
                              void* d_out, int out_size, void* d_ws, size_t ws_size,
                              hipStream_t stream) {
  const float* x = (const float*)d_in[0];
  float* out = (float*)d_out;
  if (ws_size >= 24 * sizeof(unsigned long long)) {
    ph_pass_kernel<<<24, NT, 0, stream>>>(x, out, (unsigned long long*)d_ws, 1);
  } else {
    ph_zero_kernel<<<1, 1, 0, stream>>>(out);
    ph_pass_kernel<<<24, NT, 0, stream>>>(x, out, nullptr, 0);
  }
}